// Round 4
// baseline (246.353 us; speedup 1.0000x reference)
//
#include <hip/hip_runtime.h>
#include <hip/hip_bf16.h>
#include <cstdint>
#include <cstddef>

typedef __bf16 bf16;
typedef __bf16 bf16x2_t __attribute__((ext_vector_type(2)));
typedef __bf16 bf16x4_t __attribute__((ext_vector_type(4)));
typedef __bf16 bf16x8_t __attribute__((ext_vector_type(8)));
typedef float  f32x2_t  __attribute__((ext_vector_type(2)));
typedef float  f32x4_t  __attribute__((ext_vector_type(4)));

#define NTOK 4096
#define CH   512
#define SLICE (NTOK*CH)      // 2097152 elements per blade slice
#define WSLICE (CH*CH)       // 262144 elements per weight sub-matrix

#define AS1 __attribute__((address_space(1)))
#define AS3 __attribute__((address_space(3)))

__device__ __forceinline__ void gl_lds16(const void* g, void* l) {
    __builtin_amdgcn_global_load_lds((const AS1 unsigned int*)g,
                                     (AS3 unsigned int*)l, 16, 0, 0);
}

// ---------------- convert x: (b,m,i) f32 -> [i][b*512+m] bf16 ----------------
__global__ __launch_bounds__(256) void k_convert_x(const float* __restrict__ x,
                                                   bf16* __restrict__ xb) {
    int p = blockIdx.x * 256 + threadIdx.x;          // 0..SLICE-1
    const f32x4_t* x4 = (const f32x4_t*)x;
    f32x4_t v0 = x4[2*p];
    f32x4_t v1 = x4[2*p+1];
    xb[0*SLICE + p] = (bf16)v0.x;
    xb[1*SLICE + p] = (bf16)v0.y;
    xb[2*SLICE + p] = (bf16)v0.z;
    xb[3*SLICE + p] = (bf16)v0.w;
    xb[4*SLICE + p] = (bf16)v1.x;
    xb[5*SLICE + p] = (bf16)v1.y;
    xb[6*SLICE + p] = (bf16)v1.z;
    xb[7*SLICE + p] = (bf16)v1.w;
}

// -------- convert all 3 weights: (n,m,s) f32 -> [s][n*512+m] bf16 -----------
__global__ __launch_bounds__(256) void k_convert_w(const float* __restrict__ w1,
                                                   const float* __restrict__ w2,
                                                   const float* __restrict__ w3,
                                                   bf16* __restrict__ w1b,
                                                   bf16* __restrict__ w2b,
                                                   bf16* __restrict__ w3b) {
    int p = blockIdx.x * 256 + threadIdx.x;          // 0..WSLICE-1
    const float* w = (blockIdx.y == 0) ? w1 : (blockIdx.y == 1) ? w2 : w3;
    bf16* wb       = (blockIdx.y == 0) ? w1b : (blockIdx.y == 1) ? w2b : w3b;
    f32x4_t v = ((const f32x4_t*)w)[p];
    wb[0*WSLICE + p] = (bf16)v.x;
    wb[1*WSLICE + p] = (bf16)v.y;
    wb[2*WSLICE + p] = (bf16)v.z;
    wb[3*WSLICE + p] = (bf16)v.w;
}

// ======================= DUAL GEMM: xl,xr = x @ {W1,W2}^T ====================
// Tile 256(M)x128(N), BK=64, 512 threads (8 waves, 2Mx4N), dbuf LDS 128KB.
// One barrier per K-step; next-tile global_load_lds issued right after the
// barrier so HBM latency hides under the 64-MFMA compute phase.
// LDS(row, chunk c) holds global chunk c ^ (row&7); read XOR-corrects.
__global__ __launch_bounds__(512, 2) void k_gemm12(const bf16* __restrict__ xb,
                                                   const bf16* __restrict__ w1b,
                                                   const bf16* __restrict__ w2b,
                                                   bf16* __restrict__ xl,
                                                   bf16* __restrict__ xr) {
    const int blade = blockIdx.z;
    const int sub = (blade == 0) ? 0 : (blade < 4) ? 1 : (blade < 7) ? 2 : 3;
    const bf16* A  = xb  + (size_t)blade * SLICE;
    const bf16* B1 = w1b + (size_t)sub * WSLICE;
    const bf16* B2 = w2b + (size_t)sub * WSLICE;
    const int tm = blockIdx.x * 256, tn = blockIdx.y * 128;

    __shared__ __align__(1024) bf16 lsA[2][256 * 64];   // 64KB
    __shared__ __align__(1024) bf16 lsB1[2][128 * 64];  // 32KB
    __shared__ __align__(1024) bf16 lsB2[2][128 * 64];  // 32KB

    const int t = threadIdx.x, lane = t & 63, wid = t >> 6;
    const int waveM = (wid >> 2) * 128, waveN = (wid & 3) * 32;

    // staging: per issue q, chunk c = q*512 + t; row = c>>3 = q*64 + (t>>3)
    const int srow = t >> 3;                            // 0..63
    const int sswz = ((t & 7) ^ (srow & 7)) * 8;        // pre-swizzled k elem off
    const bf16* Ag  = A  + (size_t)(tm + srow) * CH + sswz;
    const bf16* B1g = B1 + (size_t)(tn + srow) * CH + sswz;
    const bf16* B2g = B2 + (size_t)(tn + srow) * CH + sswz;
    const int wbase = wid * 1024;                       // wave-uniform LDS byte base

    const int xorv  = (lane & 7) << 4;
    const int kbase = (lane >> 4) * 16;

    f32x4_t accL[8][2] = {};
    f32x4_t accR[8][2] = {};

    // prologue: stage kt=0 into buf0
    {
        char* la  = (char*)lsA[0]  + wbase;
        char* lb1 = (char*)lsB1[0] + wbase;
        char* lb2 = (char*)lsB2[0] + wbase;
        #pragma unroll
        for (int q = 0; q < 4; ++q)
            gl_lds16(Ag + (size_t)q * 64 * CH, la + q * 8192);
        #pragma unroll
        for (int q = 0; q < 2; ++q) {
            gl_lds16(B1g + (size_t)q * 64 * CH, lb1 + q * 8192);
            gl_lds16(B2g + (size_t)q * 64 * CH, lb2 + q * 8192);
        }
    }

    #pragma unroll 2
    for (int kt = 0; kt < 8; ++kt) {
        const int cur = kt & 1;
        __syncthreads();                 // drains vmcnt (cur staged) + lgkmcnt
        if (kt < 7) {                    // issue next tile EARLY (overlaps MFMA)
            const int k0 = (kt + 1) * 64;
            char* la  = (char*)lsA[cur ^ 1]  + wbase;
            char* lb1 = (char*)lsB1[cur ^ 1] + wbase;
            char* lb2 = (char*)lsB2[cur ^ 1] + wbase;
            #pragma unroll
            for (int q = 0; q < 4; ++q)
                gl_lds16(Ag + (size_t)q * 64 * CH + k0, la + q * 8192);
            #pragma unroll
            for (int q = 0; q < 2; ++q) {
                gl_lds16(B1g + (size_t)q * 64 * CH + k0, lb1 + q * 8192);
                gl_lds16(B2g + (size_t)q * 64 * CH + k0, lb2 + q * 8192);
            }
        }
        const char* ca  = (const char*)lsA[cur];
        const char* cb1 = (const char*)lsB1[cur];
        const char* cb2 = (const char*)lsB2[cur];
        #pragma unroll
        for (int kk = 0; kk < 2; ++kk) {
            const int koff = kk * 64 + kbase;
            bf16x8_t af[8], b1f[2], b2f[2];
            #pragma unroll
            for (int mf = 0; mf < 8; ++mf) {
                int row = waveM + mf * 16 + (lane & 15);
                af[mf] = *(const bf16x8_t*)(ca + row * 128 + (koff ^ xorv));
            }
            #pragma unroll
            for (int nf = 0; nf < 2; ++nf) {
                int row = waveN + nf * 16 + (lane & 15);
                b1f[nf] = *(const bf16x8_t*)(cb1 + row * 128 + (koff ^ xorv));
                b2f[nf] = *(const bf16x8_t*)(cb2 + row * 128 + (koff ^ xorv));
            }
            __builtin_amdgcn_s_setprio(1);
            #pragma unroll
            for (int mf = 0; mf < 8; ++mf)
                #pragma unroll
                for (int nf = 0; nf < 2; ++nf) {
                    accL[mf][nf] = __builtin_amdgcn_mfma_f32_16x16x32_bf16(
                        af[mf], b1f[nf], accL[mf][nf], 0, 0, 0);
                    accR[mf][nf] = __builtin_amdgcn_mfma_f32_16x16x32_bf16(
                        af[mf], b2f[nf], accR[mf][nf], 0, 0, 0);
                }
            __builtin_amdgcn_s_setprio(0);
        }
    }

    bf16* O1 = xl + (size_t)blade * SLICE;
    bf16* O2 = xr + (size_t)blade * SLICE;
    const int orow0 = tm + waveM + (lane >> 4) * 4;
    const int ocol  = tn + waveN + (lane & 15);
    #pragma unroll
    for (int mf = 0; mf < 8; ++mf)
        #pragma unroll
        for (int r = 0; r < 4; ++r) {
            size_t rowoff = (size_t)(orow0 + mf * 16 + r) * CH;
            #pragma unroll
            for (int nf = 0; nf < 2; ++nf) {
                O1[rowoff + ocol + nf * 16] = (bf16)accL[mf][nf][r];
                O2[rowoff + ocol + nf * 16] = (bf16)accR[mf][nf][r];
            }
        }
}

// ======================= SINGLE GEMM: y = gp @ W3^T ==========================
// Tile 256x256, BK=64, 512 threads (8 waves, 2Mx4N), dbuf LDS 128KB.
__global__ __launch_bounds__(512, 2) void k_gemm3(const bf16* __restrict__ gp,
                                                  const bf16* __restrict__ w3b,
                                                  bf16* __restrict__ yb) {
    const int blade = blockIdx.z;
    const int sub = (blade == 0) ? 0 : (blade < 4) ? 1 : (blade < 7) ? 2 : 3;
    const bf16* A = gp  + (size_t)blade * SLICE;
    const bf16* B = w3b + (size_t)sub * WSLICE;
    const int tm = blockIdx.x * 256, tn = blockIdx.y * 256;

    __shared__ __align__(1024) bf16 lsA[2][256 * 64];   // 64KB
    __shared__ __align__(1024) bf16 lsB[2][256 * 64];   // 64KB

    const int t = threadIdx.x, lane = t & 63, wid = t >> 6;
    const int waveM = (wid >> 2) * 128, waveN = (wid & 3) * 64;

    const int srow = t >> 3;
    const int sswz = ((t & 7) ^ (srow & 7)) * 8;
    const bf16* Ag = A + (size_t)(tm + srow) * CH + sswz;
    const bf16* Bg = B + (size_t)(tn + srow) * CH + sswz;
    const int wbase = wid * 1024;

    const int xorv  = (lane & 7) << 4;
    const int kbase = (lane >> 4) * 16;

    f32x4_t acc[8][4] = {};

    {
        char* la = (char*)lsA[0] + wbase;
        char* lb = (char*)lsB[0] + wbase;
        #pragma unroll
        for (int q = 0; q < 4; ++q) {
            gl_lds16(Ag + (size_t)q * 64 * CH, la + q * 8192);
            gl_lds16(Bg + (size_t)q * 64 * CH, lb + q * 8192);
        }
    }

    #pragma unroll 2
    for (int kt = 0; kt < 8; ++kt) {
        const int cur = kt & 1;
        __syncthreads();
        if (kt < 7) {
            const int k0 = (kt + 1) * 64;
            char* la = (char*)lsA[cur ^ 1] + wbase;
            char* lb = (char*)lsB[cur ^ 1] + wbase;
            #pragma unroll
            for (int q = 0; q < 4; ++q) {
                gl_lds16(Ag + (size_t)q * 64 * CH + k0, la + q * 8192);
                gl_lds16(Bg + (size_t)q * 64 * CH + k0, lb + q * 8192);
            }
        }
        const char* ca = (const char*)lsA[cur];
        const char* cb = (const char*)lsB[cur];
        #pragma unroll
        for (int kk = 0; kk < 2; ++kk) {
            const int koff = kk * 64 + kbase;
            bf16x8_t af[8], bf[4];
            #pragma unroll
            for (int mf = 0; mf < 8; ++mf) {
                int row = waveM + mf * 16 + (lane & 15);
                af[mf] = *(const bf16x8_t*)(ca + row * 128 + (koff ^ xorv));
            }
            #pragma unroll
            for (int nf = 0; nf < 4; ++nf) {
                int row = waveN + nf * 16 + (lane & 15);
                bf[nf] = *(const bf16x8_t*)(cb + row * 128 + (koff ^ xorv));
            }
            __builtin_amdgcn_s_setprio(1);
            #pragma unroll
            for (int mf = 0; mf < 8; ++mf)
                #pragma unroll
                for (int nf = 0; nf < 4; ++nf)
                    acc[mf][nf] = __builtin_amdgcn_mfma_f32_16x16x32_bf16(
                        af[mf], bf[nf], acc[mf][nf], 0, 0, 0);
            __builtin_amdgcn_s_setprio(0);
        }
    }

    bf16* O = yb + (size_t)blade * SLICE;
    const int orow0 = tm + waveM + (lane >> 4) * 4;
    const int ocol  = tn + waveN + (lane & 15);
    #pragma unroll
    for (int mf = 0; mf < 8; ++mf)
        #pragma unroll
        for (int r = 0; r < 4; ++r) {
            size_t rowoff = (size_t)(orow0 + mf * 16 + r) * CH;
            #pragma unroll
            for (int nf = 0; nf < 4; ++nf)
                O[rowoff + ocol + nf * 16] = (bf16)acc[mf][nf][r];
        }
}

// ---------------- geometric product (elementwise per (b,n)) -----------------
// blade order: masks sorted by (popcount, value): [0,1,2,4,3,5,6,7]
// -> idx<->mask permutation is the transposition 3<->4 (self-inverse).
// sign(a_mask,b_mask) = (-1)^( ((a1^a2)&b0) ^ (a2&b1) )
__global__ __launch_bounds__(256) void k_gp(const bf16* __restrict__ xl,
                                            const bf16* __restrict__ xr,
                                            const float* __restrict__ b1,
                                            const float* __restrict__ b2,
                                            bf16* __restrict__ gp) {
    int p = (blockIdx.x * 256 + threadIdx.x) * 4;
    float l[8][4], r[8][4], g[8][4];
    #pragma unroll
    for (int i = 0; i < 8; ++i) {
        bf16x4_t lv = *(const bf16x4_t*)(xl + (size_t)i * SLICE + p);
        bf16x4_t rv = *(const bf16x4_t*)(xr + (size_t)i * SLICE + p);
        #pragma unroll
        for (int v = 0; v < 4; ++v) { l[i][v] = (float)lv[v]; r[i][v] = (float)rv[v]; g[i][v] = 0.f; }
    }
    int n0 = p & (CH - 1);
    f32x4_t b1v = *(const f32x4_t*)(b1 + n0);
    f32x4_t b2v = *(const f32x4_t*)(b2 + n0);
    #pragma unroll
    for (int v = 0; v < 4; ++v) { l[0][v] += b1v[v]; r[0][v] += b2v[v]; }

    const int IDX[8] = {0, 1, 2, 4, 3, 5, 6, 7};
    #pragma unroll
    for (int a = 0; a < 8; ++a) {
        #pragma unroll
        for (int b = 0; b < 8; ++b) {
            int e = ((((a >> 1) ^ (a >> 2)) & b) & 1) ^ (((a >> 2) & (b >> 1)) & 1);
            int j = IDX[a ^ b], ia = IDX[a], ib = IDX[b];
            #pragma unroll
            for (int v = 0; v < 4; ++v)
                g[j][v] += e ? (-l[ia][v] * r[ib][v]) : (l[ia][v] * r[ib][v]);
        }
    }
    #pragma unroll
    for (int i = 0; i < 8; ++i) {
        bf16x4_t gv;
        #pragma unroll
        for (int v = 0; v < 4; ++v) gv[v] = (bf16)g[i][v];
        *(bf16x4_t*)(gp + (size_t)i * SLICE + p) = gv;
    }
}

// ---------------- layernorm (one block per token; y in bf16) -----------------
__global__ __launch_bounds__(256) void k_ln(const bf16* __restrict__ y,
                                            const float* __restrict__ b3,
                                            const float* __restrict__ an,
                                            float* __restrict__ out) {
    int b = blockIdx.x, t = threadIdx.x;
    int c0 = t * 2;
    size_t base = (size_t)b * CH + c0;
    float yv[2][8];
    #pragma unroll
    for (int i = 0; i < 8; ++i) {
        bf16x2_t v = *(const bf16x2_t*)(y + (size_t)i * SLICE + base);
        yv[0][i] = (float)v[0];
        yv[1][i] = (float)v[1];
    }
    f32x2_t b3v = *(const f32x2_t*)(b3 + c0);
    float nsum = 0.f;
    #pragma unroll
    for (int h = 0; h < 2; ++h) {
        yv[h][0] += b3v[h];
        float q = yv[h][0]*yv[h][0] + yv[h][1]*yv[h][1] + yv[h][2]*yv[h][2] + yv[h][3]*yv[h][3]
                - yv[h][4]*yv[h][4] - yv[h][5]*yv[h][5] - yv[h][6]*yv[h][6] - yv[h][7]*yv[h][7];
        nsum += sqrtf(sqrtf(q * q + 1e-16f));
    }
    #pragma unroll
    for (int off = 32; off; off >>= 1) nsum += __shfl_xor(nsum, off);
    __shared__ float red[4];
    if ((t & 63) == 0) red[t >> 6] = nsum;
    __syncthreads();
    float denom = (red[0] + red[1] + red[2] + red[3]) * (1.f / 512.f) + 1e-6f;
    float inv = 1.f / denom;
    f32x2_t anv = *(const f32x2_t*)(an + c0);
    float out16[16];
    #pragma unroll
    for (int h = 0; h < 2; ++h) {
        float s = anv[h] * inv;
        #pragma unroll
        for (int i = 0; i < 8; ++i) out16[h * 8 + i] = yv[h][i] * s;
    }
    size_t base8 = base * 8;
    #pragma unroll
    for (int j = 0; j < 4; ++j)
        *(f32x4_t*)(out + base8 + j * 4) = *(f32x4_t*)(out16 + j * 4);
}

extern "C" void kernel_launch(void* const* d_in, const int* in_sizes, int n_in,
                              void* d_out, int out_size, void* d_ws, size_t ws_size,
                              hipStream_t stream) {
    (void)in_sizes; (void)n_in; (void)out_size; (void)ws_size;
    const float* x  = (const float*)d_in[0];
    const float* w1 = (const float*)d_in[1];
    const float* b1 = (const float*)d_in[2];
    const float* w2 = (const float*)d_in[3];
    const float* b2 = (const float*)d_in[4];
    const float* w3 = (const float*)d_in[5];
    const float* b3 = (const float*)d_in[6];
    const float* an = (const float*)d_in[7];

    char* ws = (char*)d_ws;
    // [xb/gp 32MB][xl 32MB -> y bf16][xr 32MB][w1b 2MB][w2b 2MB][w3b 2MB]
    bf16*  xb  = (bf16*)(ws);
    bf16*  xl  = (bf16*)(ws + 33554432);
    bf16*  xr  = (bf16*)(ws + 67108864);
    bf16*  yb  = (bf16*)(ws + 33554432);   // reuses xl after k_gp consumed it
    bf16*  w1b = (bf16*)(ws + 100663296);
    bf16*  w2b = (bf16*)(ws + 102760448);
    bf16*  w3b = (bf16*)(ws + 104857600);

    k_convert_x<<<SLICE / 256, 256, 0, stream>>>(x, xb);
    dim3 gw(WSLICE / 256, 3);
    k_convert_w<<<gw, 256, 0, stream>>>(w1, w2, w3, w1b, w2b, w3b);

    dim3 g12(NTOK / 256, CH / 128, 8);
    k_gemm12<<<g12, 512, 0, stream>>>(xb, w1b, w2b, xl, xr);
    k_gp<<<SLICE / 4 / 256, 256, 0, stream>>>(xl, xr, b1, b2, xb /* gp -> xb */);
    dim3 g3(NTOK / 256, CH / 256, 8);
    k_gemm3<<<g3, 512, 0, stream>>>(xb, w3b, yb);
    k_ln<<<NTOK, 256, 0, stream>>>(yb, b3, an, (float*)d_out);
}